// Round 6
// baseline (211.408 us; speedup 1.0000x reference)
//
#include <hip/hip_runtime.h>
#include <math.h>

constexpr int B_  = 2;
constexpr int N_  = 10000;
constexpr int E_  = 160000;
constexpr int H_  = 128;
constexpr int ET_ = 8;
constexpr float EPS_ = 1e-5f;
constexpr float RSQH = 0.08838834764831845f; // 1/sqrt(128)

typedef __bf16 bf16x8 __attribute__((ext_vector_type(8)));
typedef short  short8 __attribute__((ext_vector_type(8)));
typedef float  f32x4  __attribute__((ext_vector_type(4)));
typedef unsigned short u16;

__device__ inline u16 bf16b(float f) {
    return __builtin_bit_cast(u16, (__bf16)f);
}

__device__ inline bf16x8 ldfrag(const u16* __restrict__ W, int kc, int nt, int lane) {
    short8 s = *(const short8*)(W + ((kc * 8 + nt) * 64 + lane) * 8);
    return __builtin_bit_cast(bf16x8, s);
}

// ---------------------------------------------------------------------------
// Fused setup: blocks [0,56) weight-prep, [56,64) edge-type tables,
// [64,689) tgt histogram.  (unchanged)
// ---------------------------------------------------------------------------
__global__ __launch_bounds__(256)
void setup_kernel(const float* __restrict__ W1, const float* __restrict__ W2,
                  const float* __restrict__ Wq, const float* __restrict__ Wk,
                  const float* __restrict__ Wv,
                  u16* __restrict__ W1s, u16* __restrict__ W2s,
                  u16* __restrict__ Wqs, u16* __restrict__ Wks, u16* __restrict__ Wvs,
                  const float* __restrict__ edge_emb,
                  const float* __restrict__ bk, const float* __restrict__ bv,
                  const float* __restrict__ We, const float* __restrict__ be,
                  float* __restrict__ Kt, float* __restrict__ Vt, float* __restrict__ eb,
                  const int* __restrict__ tgt, int* __restrict__ hist)
{
    const int bid = blockIdx.x, tid = threadIdx.x;
    if (bid < 56) {
        int unit = bid >> 1, half = bid & 1;
        const float* src; u16* dst; int kc;
        if (unit < 12)      { src = W1; dst = W1s; kc = unit; }
        else if (unit < 16) { src = W2; dst = W2s; kc = unit - 12; }
        else if (unit < 20) { src = Wq; dst = Wqs; kc = unit - 16; }
        else if (unit < 24) { src = Wk; dst = Wks; kc = unit - 20; }
        else                { src = Wv; dst = Wvs; kc = unit - 24; }
        int nt = half * 4 + (tid >> 6), lane = tid & 63;
        int q = lane >> 4, c = lane & 15;
        int kbase = kc * 32 + q * 8;
        int col = nt * 16 + c;
        u16* out = dst + ((kc * 8 + nt) * 64 + lane) * 8;
#pragma unroll
        for (int j = 0; j < 8; ++j)
            out[j] = bf16b(src[(kbase + j) * H_ + col]);
    } else if (bid < 64) {
        int t = bid - 56;
        const float* ep = edge_emb + t * H_;
        __shared__ float red[2];
        int j = tid;
        if (j < 128) {
            float ak = bk[j], av = bv[j];
            for (int d = 0; d < H_; d += 4) {
                float e0 = ep[d], e1 = ep[d+1], e2 = ep[d+2], e3 = ep[d+3];
                ak += e0*Wk[(d+0)*H_+j] + e1*Wk[(d+1)*H_+j] + e2*Wk[(d+2)*H_+j] + e3*Wk[(d+3)*H_+j];
                av += e0*Wv[(d+0)*H_+j] + e1*Wv[(d+1)*H_+j] + e2*Wv[(d+2)*H_+j] + e3*Wv[(d+3)*H_+j];
            }
            Kt[t*H_ + j] = ak;
            Vt[t*H_ + j] = av;
            float pe = ep[j] * We[j];
#pragma unroll
            for (int off = 32; off; off >>= 1) pe += __shfl_xor(pe, off);
            if ((j & 63) == 0) red[j >> 6] = pe;
        }
        __syncthreads();
        if (j == 0) eb[t] = red[0] + red[1] + be[0];
    } else {
        int e = (bid - 64) * 256 + tid;
        if (e < E_) atomicAdd(&hist[tgt[e]], 1);
    }
}

// ---------------------------------------------------------------------------
// Single-pass exclusive scan: 1024 threads x 10 elements, 2 barriers.
// ---------------------------------------------------------------------------
__global__ __launch_bounds__(1024)
void scan_kernel(const int* __restrict__ hist, int* __restrict__ offs,
                 int* __restrict__ cursor)
{
    __shared__ int winc[16];
    const int tid = threadIdx.x, wave = tid >> 6, lane = tid & 63;
    int v[10];
    const int idx0 = tid * 10;
    int tot = 0;
#pragma unroll
    for (int i = 0; i < 10; ++i) {
        int idx = idx0 + i;
        v[i] = (idx < N_) ? hist[idx] : 0;
        tot += v[i];
    }
    int s = tot;
#pragma unroll
    for (int off = 1; off < 64; off <<= 1) {
        int t = __shfl_up(s, off);
        if (lane >= off) s += t;
    }
    if (lane == 63) winc[wave] = s;
    __syncthreads();
    if (tid < 16) {
        int si = winc[tid];
#pragma unroll
        for (int off = 1; off < 16; off <<= 1) {
            int t = __shfl_up(si, off);
            if (tid >= off) si += t;
        }
        winc[tid] = si;
    }
    __syncthreads();
    int wbase = (wave == 0) ? 0 : winc[wave - 1];
    int run = wbase + (s - tot);
#pragma unroll
    for (int i = 0; i < 10; ++i) {
        int idx = idx0 + i;
        if (idx < N_) { offs[idx] = run; cursor[idx] = run; }
        run += v[i];
    }
    if (tid == 0) offs[N_] = winc[15];
}

// ---------------------------------------------------------------------------
// Fused scatter (blocks [0,625)) + Q/K/V MFMA (blocks [625,938)).  Unchanged.
// ---------------------------------------------------------------------------
__global__ __launch_bounds__(256)
void scatter_qkv_kernel(const int* __restrict__ src, const int* __restrict__ tgt,
                        const int* __restrict__ type, int* __restrict__ cursor,
                        int* __restrict__ sorted,
                        const float* __restrict__ hidden, const float* __restrict__ time_emb,
                        const u16* __restrict__ Wqs, const u16* __restrict__ Wks,
                        const u16* __restrict__ Wvs, const float* __restrict__ bq,
                        u16* __restrict__ Q, u16* __restrict__ K, u16* __restrict__ V)
{
    if (blockIdx.x < 625) {
        int e = blockIdx.x * 256 + threadIdx.x;
        if (e < E_) {
            int t = tgt[e];
            int pos = atomicAdd(&cursor[t], 1);
            sorted[pos] = src[e] | (type[e] << 16);
        }
        return;
    }
    const int wv = threadIdx.x >> 6, lane = threadIdx.x & 63;
    const int tile = (blockIdx.x - 625) * 4 + wv;
    if (tile >= (B_ * N_) / 16) return;
    const int nbase = tile * 16;
    const int m = lane & 15, q = lane >> 4;
    const int koff = q * 8;

    bf16x8 aq[4], av[4];
    const float* hp = hidden   + (nbase + m) * H_ + koff;
    const float* tp = time_emb + (nbase + m) * H_ + koff;
#pragma unroll
    for (int kc = 0; kc < 4; ++kc) {
        float4 h0 = *(const float4*)(hp + kc * 32);
        float4 h1 = *(const float4*)(hp + kc * 32 + 4);
        float4 t0 = *(const float4*)(tp + kc * 32);
        float4 t1 = *(const float4*)(tp + kc * 32 + 4);
        bf16x8 fv, fq;
        fv[0]=(__bf16)h0.x; fv[1]=(__bf16)h0.y; fv[2]=(__bf16)h0.z; fv[3]=(__bf16)h0.w;
        fv[4]=(__bf16)h1.x; fv[5]=(__bf16)h1.y; fv[6]=(__bf16)h1.z; fv[7]=(__bf16)h1.w;
        fq[0]=(__bf16)(h0.x+t0.x); fq[1]=(__bf16)(h0.y+t0.y);
        fq[2]=(__bf16)(h0.z+t0.z); fq[3]=(__bf16)(h0.w+t0.w);
        fq[4]=(__bf16)(h1.x+t1.x); fq[5]=(__bf16)(h1.y+t1.y);
        fq[6]=(__bf16)(h1.z+t1.z); fq[7]=(__bf16)(h1.w+t1.w);
        av[kc] = fv; aq[kc] = fq;
    }

    f32x4 accq[8], acck[8], accv[8];
#pragma unroll
    for (int nt = 0; nt < 8; ++nt) { accq[nt] = (f32x4)0.f; acck[nt] = (f32x4)0.f; accv[nt] = (f32x4)0.f; }

#pragma unroll
    for (int kc = 0; kc < 4; ++kc) {
#pragma unroll
        for (int nt = 0; nt < 8; ++nt) {
            bf16x8 bfq = ldfrag(Wqs, kc, nt, lane);
            bf16x8 bfk = ldfrag(Wks, kc, nt, lane);
            bf16x8 bfv = ldfrag(Wvs, kc, nt, lane);
            accq[nt] = __builtin_amdgcn_mfma_f32_16x16x32_bf16(aq[kc], bfq, accq[nt], 0, 0, 0);
            acck[nt] = __builtin_amdgcn_mfma_f32_16x16x32_bf16(aq[kc], bfk, acck[nt], 0, 0, 0);
            accv[nt] = __builtin_amdgcn_mfma_f32_16x16x32_bf16(av[kc], bfv, accv[nt], 0, 0, 0);
        }
    }

#pragma unroll
    for (int nt = 0; nt < 8; ++nt) {
        int col = nt * 16 + m;
        float bqc = bq[col];
#pragma unroll
        for (int r = 0; r < 4; ++r) {
            int node = nbase + q * 4 + r;
            Q[node * H_ + col] = bf16b(accq[nt][r] + bqc);
            K[node * H_ + col] = bf16b(acck[nt][r]);
            V[node * H_ + col] = bf16b(accv[nt][r]);
        }
    }
}

// ---------------------------------------------------------------------------
// FUSED attention + MLP, 1024-thread blocks (16 waves).
//   Phase A: wave i = node i of the 16-node tile (R2 inner loop verbatim);
//            agg -> LDS.  16 waves/block restores 20000 total waves (the R5
//            4-wave version had 5000 -> 26% occupancy, latency-bound).
//   Phase B: waves 0..7 each compute one 16-col tile of the MLP; LN partials
//            combined across waves in LDS; waves 8..15 idle through barriers.
// ---------------------------------------------------------------------------
__global__ __launch_bounds__(1024)
void attn_mlp_kernel(const u16* __restrict__ Qb, const u16* __restrict__ Kb,
                     const u16* __restrict__ Vb,
                     const float* __restrict__ Kt, const float* __restrict__ Vt,
                     const float* __restrict__ eb,
                     const int* __restrict__ offs, const int* __restrict__ sorted,
                     const float* __restrict__ hidden, const float* __restrict__ time_emb,
                     const u16* __restrict__ W1s, const u16* __restrict__ W2s,
                     const float* __restrict__ b1, const float* __restrict__ b2,
                     const float* __restrict__ gamma, const float* __restrict__ beta,
                     float* __restrict__ out)
{
    __shared__ float bias_s[16][8];
    __shared__ __align__(16) u16 vt_s[8][128];
    __shared__ __align__(16) u16 agg_s[16][136];   // 272B rows: 16B-aligned, 2-way alias free
    __shared__ __align__(16) u16 h1s[16][136];
    __shared__ float sp[16][8], ssp[16][8];

    const int tid = threadIdx.x;
    const int wv = tid >> 6, lane = tid & 63;
    const int g = lane >> 4, lam = lane & 15;

    if (tid < ET_ * H_)
        vt_s[tid >> 7][tid & 127] = bf16b(Vt[tid]);
    __syncthreads();

    const int nbase = blockIdx.x * 16;
    const int b = (nbase >= N_) ? 1 : 0;
    const int n0 = nbase - b * N_;
    const u16* __restrict__ Kbb = Kb + (size_t)(b * N_) * H_;
    const u16* __restrict__ Vbb = Vb + (size_t)(b * N_) * H_;

    // ---- Phase A: one wave per node ----
    {
        const int nl = wv;                 // local node 0..15
        const int n = n0 + nl;
        const int bn = nbase + nl;
        const int beg = offs[n], end = offs[n + 1];

        float q[8];
        {
            short8 s8 = *(const short8*)(Qb + (size_t)bn * H_ + lam * 8);
            bf16x8 qa = __builtin_bit_cast(bf16x8, s8);
#pragma unroll
            for (int j = 0; j < 8; ++j) q[j] = (float)qa[j];
        }

        {   // per-type logit bias: group g computes types 2g, 2g+1
            const float* k0p = Kt + (2 * g) * H_ + lam * 8;
            const float* k1p = Kt + (2 * g + 1) * H_ + lam * 8;
            float p0 = 0.f, p1 = 0.f;
#pragma unroll
            for (int j = 0; j < 8; ++j) { p0 += q[j] * k0p[j]; p1 += q[j] * k1p[j]; }
#pragma unroll
            for (int msk = 1; msk < 16; msk <<= 1) {
                p0 += __shfl_xor(p0, msk);
                p1 += __shfl_xor(p1, msk);
            }
            if (lam == 0) {
                bias_s[wv][2 * g]     = p0 * RSQH + eb[2 * g];
                bias_s[wv][2 * g + 1] = p1 * RSQH + eb[2 * g + 1];
            }
        }
        // bias_s row written/read by the same wave -> wave-synchronous

        float m_g = -INFINITY, l_g = 0.f;
        float acc[8];
#pragma unroll
        for (int j = 0; j < 8; ++j) acc[j] = 0.f;

        int c = beg + g;
        for (; c + 4 < end; c += 8) {
            int pk0 = sorted[c];
            int pk1 = sorted[c + 4];
            int s0 = pk0 & 0xFFFF, t0 = pk0 >> 16;
            int s1 = pk1 & 0xFFFF, t1 = pk1 >> 16;
            short8 k80 = *(const short8*)(Kbb + (size_t)s0 * H_ + lam * 8);
            short8 k81 = *(const short8*)(Kbb + (size_t)s1 * H_ + lam * 8);
            short8 v80 = *(const short8*)(Vbb + (size_t)s0 * H_ + lam * 8);
            short8 v81 = *(const short8*)(Vbb + (size_t)s1 * H_ + lam * 8);
            short8 vt80 = *(const short8*)(&vt_s[t0][lam * 8]);
            short8 vt81 = *(const short8*)(&vt_s[t1][lam * 8]);
            bf16x8 ka0 = __builtin_bit_cast(bf16x8, k80);
            bf16x8 ka1 = __builtin_bit_cast(bf16x8, k81);
            float p0 = 0.f, p1 = 0.f;
#pragma unroll
            for (int j = 0; j < 8; ++j) {
                p0 += q[j] * (float)ka0[j];
                p1 += q[j] * (float)ka1[j];
            }
#pragma unroll
            for (int msk = 1; msk < 16; msk <<= 1) {
                p0 += __shfl_xor(p0, msk);
                p1 += __shfl_xor(p1, msk);
            }
            float lg0 = p0 * RSQH + bias_s[wv][t0];
            float lg1 = p1 * RSQH + bias_s[wv][t1];
            float mx = fmaxf(lg0, lg1);
            if (mx > m_g + 8.f) {          // deferred rescale (T13)
                float rs = __expf(m_g - mx);   // first trigger: exp(-inf)=0
                l_g *= rs;
#pragma unroll
                for (int j = 0; j < 8; ++j) acc[j] *= rs;
                m_g = mx;
            }
            float w0 = __expf(lg0 - m_g);
            float w1 = __expf(lg1 - m_g);
            l_g += w0 + w1;
            bf16x8 va0  = __builtin_bit_cast(bf16x8, v80);
            bf16x8 va1  = __builtin_bit_cast(bf16x8, v81);
            bf16x8 vta0 = __builtin_bit_cast(bf16x8, vt80);
            bf16x8 vta1 = __builtin_bit_cast(bf16x8, vt81);
#pragma unroll
            for (int j = 0; j < 8; ++j)
                acc[j] += w0 * ((float)va0[j] + (float)vta0[j])
                        + w1 * ((float)va1[j] + (float)vta1[j]);
        }
        if (c < end) {
            int pk0 = sorted[c];
            int s0 = pk0 & 0xFFFF, t0 = pk0 >> 16;
            short8 k80 = *(const short8*)(Kbb + (size_t)s0 * H_ + lam * 8);
            short8 v80 = *(const short8*)(Vbb + (size_t)s0 * H_ + lam * 8);
            short8 vt80 = *(const short8*)(&vt_s[t0][lam * 8]);
            bf16x8 ka0 = __builtin_bit_cast(bf16x8, k80);
            float p0 = 0.f;
#pragma unroll
            for (int j = 0; j < 8; ++j) p0 += q[j] * (float)ka0[j];
#pragma unroll
            for (int msk = 1; msk < 16; msk <<= 1) p0 += __shfl_xor(p0, msk);
            float lg0 = p0 * RSQH + bias_s[wv][t0];
            if (lg0 > m_g + 8.f) {
                float rs = __expf(m_g - lg0);
                l_g *= rs;
#pragma unroll
                for (int j = 0; j < 8; ++j) acc[j] *= rs;
                m_g = lg0;
            }
            float w0 = __expf(lg0 - m_g);
            l_g += w0;
            bf16x8 va0  = __builtin_bit_cast(bf16x8, v80);
            bf16x8 vta0 = __builtin_bit_cast(bf16x8, vt80);
#pragma unroll
            for (int j = 0; j < 8; ++j)
                acc[j] += w0 * ((float)va0[j] + (float)vta0[j]);
        }

        // merge the 4 groups: max + rescale + sum
        float M = fmaxf(m_g, __shfl_xor(m_g, 16));
        M = fmaxf(M, __shfl_xor(M, 32));
        float rs = (m_g == M) ? 1.f : __expf(m_g - M);  // guards -inf - -inf = NaN
        l_g *= rs;
#pragma unroll
        for (int j = 0; j < 8; ++j) {
            acc[j] *= rs;
            acc[j] += __shfl_xor(acc[j], 16);
            acc[j] += __shfl_xor(acc[j], 32);
        }
        l_g += __shfl_xor(l_g, 16);
        l_g += __shfl_xor(l_g, 32);

        if (g == 0) {
            float invL = (end > beg) ? 1.f / l_g : 0.f;
            bf16x8 o;
#pragma unroll
            for (int j = 0; j < 8; ++j) o[j] = (__bf16)(acc[j] * invL);
            *(short8*)(&agg_s[nl][lam * 8]) = __builtin_bit_cast(short8, o);
        }
    }
    __syncthreads();

    // ---- Phase B: MLP + residual + LayerNorm on waves 0..7 ----
    const int m = lane & 15, q = lane >> 4;
    const int koff = q * 8;
    float x[4];
    f32x4 acc2;

    if (wv < 8) {
        bf16x8 a[12];
        const float* hp = hidden   + (size_t)(nbase + m) * H_ + koff;
        const float* tp = time_emb + (size_t)(nbase + m) * H_ + koff;
#pragma unroll
        for (int kc = 0; kc < 4; ++kc) {
            float4 h0 = *(const float4*)(hp + kc * 32);
            float4 h1 = *(const float4*)(hp + kc * 32 + 4);
            float4 t0 = *(const float4*)(tp + kc * 32);
            float4 t1 = *(const float4*)(tp + kc * 32 + 4);
            bf16x8 fh, ft;
            fh[0]=(__bf16)h0.x; fh[1]=(__bf16)h0.y; fh[2]=(__bf16)h0.z; fh[3]=(__bf16)h0.w;
            fh[4]=(__bf16)h1.x; fh[5]=(__bf16)h1.y; fh[6]=(__bf16)h1.z; fh[7]=(__bf16)h1.w;
            ft[0]=(__bf16)t0.x; ft[1]=(__bf16)t0.y; ft[2]=(__bf16)t0.z; ft[3]=(__bf16)t0.w;
            ft[4]=(__bf16)t1.x; ft[5]=(__bf16)t1.y; ft[6]=(__bf16)t1.z; ft[7]=(__bf16)t1.w;
            a[0 * 4 + kc] = fh;
            a[2 * 4 + kc] = ft;
            short8 s8 = *(const short8*)(&agg_s[m][kc * 32 + koff]);
            a[1 * 4 + kc] = __builtin_bit_cast(bf16x8, s8);
        }

        // GEMM1: this wave computes column tile nt = wv
        f32x4 acc1 = (f32x4)0.f;
#pragma unroll
        for (int kc = 0; kc < 12; ++kc) {
            bf16x8 bf = ldfrag(W1s, kc, wv, lane);
            acc1 = __builtin_amdgcn_mfma_f32_16x16x32_bf16(a[kc], bf, acc1, 0, 0, 0);
        }
        int col = wv * 16 + m;
        float bb = b1[col];
#pragma unroll
        for (int r = 0; r < 4; ++r) {
            float v = acc1[r] + bb;
            float h = v / (1.f + __expf(-v));
            h1s[q * 4 + r][col] = bf16b(h);
        }
    }
    __syncthreads();

    if (wv < 8) {
        acc2 = (f32x4)0.f;
#pragma unroll
        for (int kc = 0; kc < 4; ++kc) {
            short8 s8 = *(const short8*)(&h1s[m][kc * 32 + koff]);
            bf16x8 a2 = __builtin_bit_cast(bf16x8, s8);
            bf16x8 bf = ldfrag(W2s, kc, wv, lane);
            acc2 = __builtin_amdgcn_mfma_f32_16x16x32_bf16(a2, bf, acc2, 0, 0, 0);
        }

        int col = wv * 16 + m;
        float bb = b2[col];
#pragma unroll
        for (int r = 0; r < 4; ++r) {
            int node = nbase + q * 4 + r;
            x[r] = hidden[(size_t)node * H_ + col] + acc2[r] + bb;
        }
        // per-wave partial LN sums (16 of the 128 cols per node)
#pragma unroll
        for (int r = 0; r < 4; ++r) {
            float s  = x[r];
            float ss = x[r] * x[r];
#pragma unroll
            for (int off = 1; off < 16; off <<= 1) {
                s  += __shfl_xor(s, off);
                ss += __shfl_xor(ss, off);
            }
            if (m == 0) { sp[q * 4 + r][wv] = s; ssp[q * 4 + r][wv] = ss; }
        }
    }
    __syncthreads();

    if (wv < 8) {
        int col = wv * 16 + m;
#pragma unroll
        for (int r = 0; r < 4; ++r) {
            int nl = q * 4 + r;
            float s  = (sp[nl][0]  + sp[nl][1])  + (sp[nl][2]  + sp[nl][3])
                     + (sp[nl][4]  + sp[nl][5])  + (sp[nl][6]  + sp[nl][7]);
            float ss = (ssp[nl][0] + ssp[nl][1]) + (ssp[nl][2] + ssp[nl][3])
                     + (ssp[nl][4] + ssp[nl][5]) + (ssp[nl][6] + ssp[nl][7]);
            float mu  = s * (1.f / H_);
            float var = ss * (1.f / H_) - mu * mu;
            float rsn = rsqrtf(var + EPS_);
            int node = nbase + nl;
            out[(size_t)node * H_ + col] = (x[r] - mu) * rsn * gamma[col] + beta[col];
        }
    }
}

// ---------------------------------------------------------------------------
extern "C" void kernel_launch(void* const* d_in, const int* in_sizes, int n_in,
                              void* d_out, int out_size, void* d_ws, size_t ws_size,
                              hipStream_t stream)
{
    const float* hidden   = (const float*)d_in[0];
    const float* time_emb = (const float*)d_in[1];
    const int*   eidx     = (const int*)d_in[2];
    const int*   etype    = (const int*)d_in[3];
    const float* edge_emb = (const float*)d_in[4];
    const float* Wq = (const float*)d_in[5];
    const float* bq = (const float*)d_in[6];
    const float* Wk = (const float*)d_in[7];
    const float* bk = (const float*)d_in[8];
    const float* Wv = (const float*)d_in[9];
    const float* bv = (const float*)d_in[10];
    const float* We = (const float*)d_in[11];
    const float* be = (const float*)d_in[12];
    const float* W1 = (const float*)d_in[13];
    const float* b1 = (const float*)d_in[14];
    const float* W2 = (const float*)d_in[15];
    const float* b2 = (const float*)d_in[16];
    const float* gamma = (const float*)d_in[17];
    const float* beta  = (const float*)d_in[18];
    float* out = (float*)d_out;

    constexpr int BNH = B_ * N_ * H_;
    u16* Qb   = (u16*)d_ws;
    u16* Kb   = Qb + BNH;
    u16* Vb   = Kb + BNH;
    float* Kt  = (float*)(Vb + BNH);
    float* Vt  = Kt + ET_ * H_;
    float* ebt = Vt + ET_ * H_;
    int* hist   = (int*)(ebt + ET_);
    int* offs   = hist + N_;
    int* cursor = offs + (N_ + 1);
    int* sorted = cursor + N_;
    uintptr_t wp = (uintptr_t)(sorted + E_);
    wp = (wp + 15) & ~(uintptr_t)15;
    u16* W1s = (u16*)wp;
    u16* W2s = W1s + 384 * 128;
    u16* Wqs = W2s + 128 * 128;
    u16* Wks = Wqs + 128 * 128;
    u16* Wvs = Wks + 128 * 128;

    const int* esrc = eidx;
    const int* etgt = eidx + E_;

    hipMemsetAsync(hist, 0, N_ * sizeof(int), stream);

    setup_kernel<<<64 + (E_ + 255) / 256, 256, 0, stream>>>(
        W1, W2, Wq, Wk, Wv, W1s, W2s, Wqs, Wks, Wvs,
        edge_emb, bk, bv, We, be, Kt, Vt, ebt, etgt, hist);
    scan_kernel<<<1, 1024, 0, stream>>>(hist, offs, cursor);
    scatter_qkv_kernel<<<625 + 313, 256, 0, stream>>>(
        esrc, etgt, etype, cursor, sorted,
        hidden, time_emb, Wqs, Wks, Wvs, bq, Qb, Kb, Vb);
    attn_mlp_kernel<<<(B_ * N_) / 16, 1024, 0, stream>>>(
        Qb, Kb, Vb, Kt, Vt, ebt, offs, sorted,
        hidden, time_emb, W1s, W2s, b1, b2, gamma, beta, out);
}

// Round 7
// 174.640 us; speedup vs baseline: 1.2105x; 1.2105x over previous
//
#include <hip/hip_runtime.h>
#include <math.h>

constexpr int B_  = 2;
constexpr int N_  = 10000;
constexpr int E_  = 160000;
constexpr int H_  = 128;
constexpr int ET_ = 8;
constexpr int CAP_ = 64;               // slots per tgt node; P(deg>=64) ~ 2e-18
constexpr float EPS_ = 1e-5f;
constexpr float RSQH = 0.08838834764831845f; // 1/sqrt(128)

typedef __bf16 bf16x8 __attribute__((ext_vector_type(8)));
typedef short  short8 __attribute__((ext_vector_type(8)));
typedef float  f32x4  __attribute__((ext_vector_type(4)));
typedef unsigned short u16;

__device__ inline u16 bf16b(float f) {
    return __builtin_bit_cast(u16, (__bf16)f);
}

__device__ inline bf16x8 ldfrag(const u16* __restrict__ W, int kc, int nt, int lane) {
    short8 s = *(const short8*)(W + ((kc * 8 + nt) * 64 + lane) * 8);
    return __builtin_bit_cast(bf16x8, s);
}

// ---------------------------------------------------------------------------
// Setup: blocks [0,56) weight-prep, [56,64) edge-type tables,
// [64,74) zero count[] (replaces the hipMemsetAsync dispatch).
// No histogram, no scan — scatter allocates slots directly next dispatch.
// ---------------------------------------------------------------------------
__global__ __launch_bounds__(256)
void setup_kernel(const float* __restrict__ W1, const float* __restrict__ W2,
                  const float* __restrict__ Wq, const float* __restrict__ Wk,
                  const float* __restrict__ Wv,
                  u16* __restrict__ W1s, u16* __restrict__ W2s,
                  u16* __restrict__ Wqs, u16* __restrict__ Wks, u16* __restrict__ Wvs,
                  const float* __restrict__ edge_emb,
                  const float* __restrict__ bk, const float* __restrict__ bv,
                  const float* __restrict__ We, const float* __restrict__ be,
                  float* __restrict__ Kt, float* __restrict__ Vt, float* __restrict__ eb,
                  int* __restrict__ count)
{
    const int bid = blockIdx.x, tid = threadIdx.x;
    if (bid < 56) {
        int unit = bid >> 1, half = bid & 1;
        const float* src; u16* dst; int kc;
        if (unit < 12)      { src = W1; dst = W1s; kc = unit; }
        else if (unit < 16) { src = W2; dst = W2s; kc = unit - 12; }
        else if (unit < 20) { src = Wq; dst = Wqs; kc = unit - 16; }
        else if (unit < 24) { src = Wk; dst = Wks; kc = unit - 20; }
        else                { src = Wv; dst = Wvs; kc = unit - 24; }
        int nt = half * 4 + (tid >> 6), lane = tid & 63;
        int q = lane >> 4, c = lane & 15;
        int kbase = kc * 32 + q * 8;
        int col = nt * 16 + c;
        u16* out = dst + ((kc * 8 + nt) * 64 + lane) * 8;
#pragma unroll
        for (int j = 0; j < 8; ++j)
            out[j] = bf16b(src[(kbase + j) * H_ + col]);
    } else if (bid < 64) {
        int t = bid - 56;
        const float* ep = edge_emb + t * H_;
        __shared__ float red[2];
        int j = tid;
        if (j < 128) {
            float ak = bk[j], av = bv[j];
            for (int d = 0; d < H_; d += 4) {
                float e0 = ep[d], e1 = ep[d+1], e2 = ep[d+2], e3 = ep[d+3];
                ak += e0*Wk[(d+0)*H_+j] + e1*Wk[(d+1)*H_+j] + e2*Wk[(d+2)*H_+j] + e3*Wk[(d+3)*H_+j];
                av += e0*Wv[(d+0)*H_+j] + e1*Wv[(d+1)*H_+j] + e2*Wv[(d+2)*H_+j] + e3*Wv[(d+3)*H_+j];
            }
            Kt[t*H_ + j] = ak;
            Vt[t*H_ + j] = av;
            float pe = ep[j] * We[j];
#pragma unroll
            for (int off = 32; off; off >>= 1) pe += __shfl_xor(pe, off);
            if ((j & 63) == 0) red[j >> 6] = pe;
        }
        __syncthreads();
        if (j == 0) eb[t] = red[0] + red[1] + be[0];
    } else {
        int i0 = (bid - 64) * 1024;
        for (int i = i0 + tid; i < i0 + 1024; i += 256)
            if (i < N_) count[i] = 0;
    }
}

// ---------------------------------------------------------------------------
// Fused scatter (blocks [0,625)) + Q/KV MFMA (blocks [625,938)).
// Scatter: direct slot allocation (no scan/cursor).  QKV: K and V written
// INTERLEAVED per node ([node][0..127]=K, [128..255]=V) so each edge's
// gather is one contiguous 512-B region.
// ---------------------------------------------------------------------------
__global__ __launch_bounds__(256)
void scatter_qkv_kernel(const int* __restrict__ src, const int* __restrict__ tgt,
                        const int* __restrict__ type, int* __restrict__ count,
                        int* __restrict__ slots,
                        const float* __restrict__ hidden, const float* __restrict__ time_emb,
                        const u16* __restrict__ Wqs, const u16* __restrict__ Wks,
                        const u16* __restrict__ Wvs, const float* __restrict__ bq,
                        u16* __restrict__ Q, u16* __restrict__ KV)
{
    if (blockIdx.x < 625) {
        int e = blockIdx.x * 256 + threadIdx.x;
        if (e < E_) {
            int t = tgt[e];
            int pos = atomicAdd(&count[t], 1);
            slots[t * CAP_ + pos] = src[e] | (type[e] << 16);
        }
        return;
    }
    const int wv = threadIdx.x >> 6, lane = threadIdx.x & 63;
    const int tile = (blockIdx.x - 625) * 4 + wv;
    if (tile >= (B_ * N_) / 16) return;
    const int nbase = tile * 16;
    const int m = lane & 15, q = lane >> 4;
    const int koff = q * 8;

    bf16x8 aq[4], av[4];
    const float* hp = hidden   + (nbase + m) * H_ + koff;
    const float* tp = time_emb + (nbase + m) * H_ + koff;
#pragma unroll
    for (int kc = 0; kc < 4; ++kc) {
        float4 h0 = *(const float4*)(hp + kc * 32);
        float4 h1 = *(const float4*)(hp + kc * 32 + 4);
        float4 t0 = *(const float4*)(tp + kc * 32);
        float4 t1 = *(const float4*)(tp + kc * 32 + 4);
        bf16x8 fv, fq;
        fv[0]=(__bf16)h0.x; fv[1]=(__bf16)h0.y; fv[2]=(__bf16)h0.z; fv[3]=(__bf16)h0.w;
        fv[4]=(__bf16)h1.x; fv[5]=(__bf16)h1.y; fv[6]=(__bf16)h1.z; fv[7]=(__bf16)h1.w;
        fq[0]=(__bf16)(h0.x+t0.x); fq[1]=(__bf16)(h0.y+t0.y);
        fq[2]=(__bf16)(h0.z+t0.z); fq[3]=(__bf16)(h0.w+t0.w);
        fq[4]=(__bf16)(h1.x+t1.x); fq[5]=(__bf16)(h1.y+t1.y);
        fq[6]=(__bf16)(h1.z+t1.z); fq[7]=(__bf16)(h1.w+t1.w);
        av[kc] = fv; aq[kc] = fq;
    }

    f32x4 accq[8], acck[8], accv[8];
#pragma unroll
    for (int nt = 0; nt < 8; ++nt) { accq[nt] = (f32x4)0.f; acck[nt] = (f32x4)0.f; accv[nt] = (f32x4)0.f; }

#pragma unroll
    for (int kc = 0; kc < 4; ++kc) {
#pragma unroll
        for (int nt = 0; nt < 8; ++nt) {
            bf16x8 bfq = ldfrag(Wqs, kc, nt, lane);
            bf16x8 bfk = ldfrag(Wks, kc, nt, lane);
            bf16x8 bfv = ldfrag(Wvs, kc, nt, lane);
            accq[nt] = __builtin_amdgcn_mfma_f32_16x16x32_bf16(aq[kc], bfq, accq[nt], 0, 0, 0);
            acck[nt] = __builtin_amdgcn_mfma_f32_16x16x32_bf16(aq[kc], bfk, acck[nt], 0, 0, 0);
            accv[nt] = __builtin_amdgcn_mfma_f32_16x16x32_bf16(av[kc], bfv, accv[nt], 0, 0, 0);
        }
    }

#pragma unroll
    for (int nt = 0; nt < 8; ++nt) {
        int col = nt * 16 + m;
        float bqc = bq[col];
#pragma unroll
        for (int r = 0; r < 4; ++r) {
            int node = nbase + q * 4 + r;
            Q[(size_t)node * H_ + col] = bf16b(accq[nt][r] + bqc);
            KV[(size_t)node * 256 + col]       = bf16b(acck[nt][r]);
            KV[(size_t)node * 256 + 128 + col] = bf16b(accv[nt][r]);
        }
    }
}

// ---------------------------------------------------------------------------
// Attention: one wave per (b,node); 16-lane groups own edges; SINGLE-PASS
// online softmax with deferred rescale (THR=8); 2 edges in flight per group;
// slot-based edge list (count[n], slots[n*64+i]); interleaved KV gather
// (one 512-B region per edge).  Batch-contiguous block mapping: blocks
// [0,2500) = batch 0 — per-XCD L2 sees one batch's KV (5.1 MB) at a time.
// ---------------------------------------------------------------------------
__global__ __launch_bounds__(256)
void attn_kernel(const u16* __restrict__ Qb, const u16* __restrict__ KV,
                 const float* __restrict__ Kt, const float* __restrict__ Vt,
                 const float* __restrict__ eb,
                 const int* __restrict__ count, const int* __restrict__ slots,
                 u16* __restrict__ aggb)
{
    __shared__ float bias_s[4][8];
    __shared__ __align__(16) u16 vt_s[8][128];

    const int tid = threadIdx.x;
    const int wv = tid >> 6, lane = tid & 63;
    const int g = lane >> 4, lam = lane & 15;

    for (int idx = tid; idx < ET_ * H_; idx += 256)
        vt_s[idx >> 7][idx & 127] = bf16b(Vt[idx]);
    __syncthreads();

    const int b = (blockIdx.x >= (N_ / 4)) ? 1 : 0;   // batch-contiguous halves
    const int n = (blockIdx.x - b * (N_ / 4)) * 4 + wv;
    const int bn = b * N_ + n;
    const int cnt = count[n];
    const int sbase = n * CAP_;
    const u16* __restrict__ KVb = KV + (size_t)(b * N_) * 256;

    float q[8];
    {
        short8 s8 = *(const short8*)(Qb + (size_t)bn * H_ + lam * 8);
        bf16x8 qa = __builtin_bit_cast(bf16x8, s8);
#pragma unroll
        for (int j = 0; j < 8; ++j) q[j] = (float)qa[j];
    }

    {   // per-type logit bias: group g computes types 2g, 2g+1
        const float* k0p = Kt + (2 * g) * H_ + lam * 8;
        const float* k1p = Kt + (2 * g + 1) * H_ + lam * 8;
        float p0 = 0.f, p1 = 0.f;
#pragma unroll
        for (int j = 0; j < 8; ++j) { p0 += q[j] * k0p[j]; p1 += q[j] * k1p[j]; }
#pragma unroll
        for (int msk = 1; msk < 16; msk <<= 1) {
            p0 += __shfl_xor(p0, msk);
            p1 += __shfl_xor(p1, msk);
        }
        if (lam == 0) {
            bias_s[wv][2 * g]     = p0 * RSQH + eb[2 * g];
            bias_s[wv][2 * g + 1] = p1 * RSQH + eb[2 * g + 1];
        }
    }
    // bias_s row written/read by the same wave -> wave-synchronous

    float m_g = -INFINITY, l_g = 0.f;
    float acc[8];
#pragma unroll
    for (int j = 0; j < 8; ++j) acc[j] = 0.f;

    int c = g;
    for (; c + 4 < cnt; c += 8) {
        int pk0 = slots[sbase + c];
        int pk1 = slots[sbase + c + 4];
        int s0 = pk0 & 0xFFFF, t0 = pk0 >> 16;
        int s1 = pk1 & 0xFFFF, t1 = pk1 >> 16;
        // co-issue K and V for both edges (one 512-B region per edge)
        short8 k80 = *(const short8*)(KVb + (size_t)s0 * 256 + lam * 8);
        short8 k81 = *(const short8*)(KVb + (size_t)s1 * 256 + lam * 8);
        short8 v80 = *(const short8*)(KVb + (size_t)s0 * 256 + 128 + lam * 8);
        short8 v81 = *(const short8*)(KVb + (size_t)s1 * 256 + 128 + lam * 8);
        short8 vt80 = *(const short8*)(&vt_s[t0][lam * 8]);
        short8 vt81 = *(const short8*)(&vt_s[t1][lam * 8]);
        bf16x8 ka0 = __builtin_bit_cast(bf16x8, k80);
        bf16x8 ka1 = __builtin_bit_cast(bf16x8, k81);
        float p0 = 0.f, p1 = 0.f;
#pragma unroll
        for (int j = 0; j < 8; ++j) {
            p0 += q[j] * (float)ka0[j];
            p1 += q[j] * (float)ka1[j];
        }
#pragma unroll
        for (int msk = 1; msk < 16; msk <<= 1) {
            p0 += __shfl_xor(p0, msk);
            p1 += __shfl_xor(p1, msk);
        }
        float lg0 = p0 * RSQH + bias_s[wv][t0];
        float lg1 = p1 * RSQH + bias_s[wv][t1];
        float mx = fmaxf(lg0, lg1);
        if (mx > m_g + 8.f) {          // deferred rescale (T13)
            float rs = __expf(m_g - mx);   // first trigger: exp(-inf)=0
            l_g *= rs;
#pragma unroll
            for (int j = 0; j < 8; ++j) acc[j] *= rs;
            m_g = mx;
        }
        float w0 = __expf(lg0 - m_g);
        float w1 = __expf(lg1 - m_g);
        l_g += w0 + w1;
        bf16x8 va0  = __builtin_bit_cast(bf16x8, v80);
        bf16x8 va1  = __builtin_bit_cast(bf16x8, v81);
        bf16x8 vta0 = __builtin_bit_cast(bf16x8, vt80);
        bf16x8 vta1 = __builtin_bit_cast(bf16x8, vt81);
#pragma unroll
        for (int j = 0; j < 8; ++j)
            acc[j] += w0 * ((float)va0[j] + (float)vta0[j])
                    + w1 * ((float)va1[j] + (float)vta1[j]);
    }
    if (c < cnt) {
        int pk0 = slots[sbase + c];
        int s0 = pk0 & 0xFFFF, t0 = pk0 >> 16;
        short8 k80 = *(const short8*)(KVb + (size_t)s0 * 256 + lam * 8);
        short8 v80 = *(const short8*)(KVb + (size_t)s0 * 256 + 128 + lam * 8);
        short8 vt80 = *(const short8*)(&vt_s[t0][lam * 8]);
        bf16x8 ka0 = __builtin_bit_cast(bf16x8, k80);
        float p0 = 0.f;
#pragma unroll
        for (int j = 0; j < 8; ++j) p0 += q[j] * (float)ka0[j];
#pragma unroll
        for (int msk = 1; msk < 16; msk <<= 1) p0 += __shfl_xor(p0, msk);
        float lg0 = p0 * RSQH + bias_s[wv][t0];
        if (lg0 > m_g + 8.f) {
            float rs = __expf(m_g - lg0);
            l_g *= rs;
#pragma unroll
            for (int j = 0; j < 8; ++j) acc[j] *= rs;
            m_g = lg0;
        }
        float w0 = __expf(lg0 - m_g);
        l_g += w0;
        bf16x8 va0  = __builtin_bit_cast(bf16x8, v80);
        bf16x8 vta0 = __builtin_bit_cast(bf16x8, vt80);
#pragma unroll
        for (int j = 0; j < 8; ++j)
            acc[j] += w0 * ((float)va0[j] + (float)vta0[j]);
    }

    // merge the 4 groups (reconverged here): max + rescale + sum
    float M = fmaxf(m_g, __shfl_xor(m_g, 16));
    M = fmaxf(M, __shfl_xor(M, 32));
    float rs = (m_g == M) ? 1.f : __expf(m_g - M);  // guards -inf - -inf = NaN
    l_g *= rs;
#pragma unroll
    for (int j = 0; j < 8; ++j) {
        acc[j] *= rs;
        acc[j] += __shfl_xor(acc[j], 16);
        acc[j] += __shfl_xor(acc[j], 32);
    }
    l_g += __shfl_xor(l_g, 16);
    l_g += __shfl_xor(l_g, 32);

    if (g == 0) {
        float invL = (cnt > 0) ? 1.f / l_g : 0.f;
        bf16x8 o;
#pragma unroll
        for (int j = 0; j < 8; ++j) o[j] = (__bf16)(acc[j] * invL);
        *(short8*)(aggb + (size_t)bn * H_ + lam * 8) = __builtin_bit_cast(short8, o);
    }
}

// ---------------------------------------------------------------------------
// MLP + residual + LayerNorm via MFMA.  313 blocks x 4 waves (R2 form).
// ---------------------------------------------------------------------------
__global__ __launch_bounds__(256)
void mlp_mfma_kernel(const float* __restrict__ hidden, const u16* __restrict__ aggb,
                     const float* __restrict__ time_emb,
                     const u16* __restrict__ W1s, const u16* __restrict__ W2s,
                     const float* __restrict__ b1, const float* __restrict__ b2,
                     const float* __restrict__ gamma, const float* __restrict__ beta,
                     float* __restrict__ out)
{
    __shared__ __align__(16) u16 h1s[4][16][136];
    const int wv = threadIdx.x >> 6, lane = threadIdx.x & 63;
    const int tile = blockIdx.x * 4 + wv;
    if (tile >= (B_ * N_) / 16) return;
    const int nbase = tile * 16;
    const int m = lane & 15, q = lane >> 4;
    const int koff = q * 8;

    bf16x8 a[12];
    const float* hp = hidden   + (nbase + m) * H_ + koff;
    const float* tp = time_emb + (nbase + m) * H_ + koff;
    const u16*   ap = aggb + (size_t)(nbase + m) * H_ + koff;
#pragma unroll
    for (int kc = 0; kc < 4; ++kc) {
        float4 h0 = *(const float4*)(hp + kc * 32);
        float4 h1 = *(const float4*)(hp + kc * 32 + 4);
        float4 t0 = *(const float4*)(tp + kc * 32);
        float4 t1 = *(const float4*)(tp + kc * 32 + 4);
        bf16x8 fh, ft;
        fh[0]=(__bf16)h0.x; fh[1]=(__bf16)h0.y; fh[2]=(__bf16)h0.z; fh[3]=(__bf16)h0.w;
        fh[4]=(__bf16)h1.x; fh[5]=(__bf16)h1.y; fh[6]=(__bf16)h1.z; fh[7]=(__bf16)h1.w;
        ft[0]=(__bf16)t0.x; ft[1]=(__bf16)t0.y; ft[2]=(__bf16)t0.z; ft[3]=(__bf16)t0.w;
        ft[4]=(__bf16)t1.x; ft[5]=(__bf16)t1.y; ft[6]=(__bf16)t1.z; ft[7]=(__bf16)t1.w;
        a[0 * 4 + kc] = fh;
        a[2 * 4 + kc] = ft;
        short8 s8 = *(const short8*)(ap + kc * 32);
        a[1 * 4 + kc] = __builtin_bit_cast(bf16x8, s8);
    }

    f32x4 acc[8];
#pragma unroll
    for (int nt = 0; nt < 8; ++nt) acc[nt] = (f32x4)0.f;
#pragma unroll
    for (int kc = 0; kc < 12; ++kc) {
#pragma unroll
        for (int nt = 0; nt < 8; ++nt) {
            bf16x8 bf = ldfrag(W1s, kc, nt, lane);
            acc[nt] = __builtin_amdgcn_mfma_f32_16x16x32_bf16(a[kc], bf, acc[nt], 0, 0, 0);
        }
    }

#pragma unroll
    for (int nt = 0; nt < 8; ++nt) {
        int col = nt * 16 + m;
        float bb = b1[col];
#pragma unroll
        for (int r = 0; r < 4; ++r) {
            float v = acc[nt][r] + bb;
            float h = v / (1.f + __expf(-v));
            h1s[wv][q * 4 + r][col] = bf16b(h);
        }
    }

    f32x4 acc2[8];
#pragma unroll
    for (int nt = 0; nt < 8; ++nt) acc2[nt] = (f32x4)0.f;
#pragma unroll
    for (int kc = 0; kc < 4; ++kc) {
        short8 s8 = *(const short8*)&h1s[wv][m][kc * 32 + koff];
        bf16x8 a2 = __builtin_bit_cast(bf16x8, s8);
#pragma unroll
        for (int nt = 0; nt < 8; ++nt) {
            bf16x8 bf = ldfrag(W2s, kc, nt, lane);
            acc2[nt] = __builtin_amdgcn_mfma_f32_16x16x32_bf16(a2, bf, acc2[nt], 0, 0, 0);
        }
    }

    float x[8][4];
#pragma unroll
    for (int nt = 0; nt < 8; ++nt) {
        int col = nt * 16 + m;
        float bb = b2[col];
#pragma unroll
        for (int r = 0; r < 4; ++r) {
            int node = nbase + q * 4 + r;
            x[nt][r] = hidden[node * H_ + col] + acc2[nt][r] + bb;
        }
    }
#pragma unroll
    for (int r = 0; r < 4; ++r) {
        float s = 0.f, ss = 0.f;
#pragma unroll
        for (int nt = 0; nt < 8; ++nt) { s += x[nt][r]; ss += x[nt][r] * x[nt][r]; }
#pragma unroll
        for (int off = 1; off < 16; off <<= 1) {
            s  += __shfl_xor(s, off);
            ss += __shfl_xor(ss, off);
        }
        float mu  = s * (1.f / H_);
        float var = ss * (1.f / H_) - mu * mu;
        float rs  = rsqrtf(var + EPS_);
        int node = nbase + q * 4 + r;
#pragma unroll
        for (int nt = 0; nt < 8; ++nt) {
            int col = nt * 16 + m;
            out[node * H_ + col] = (x[nt][r] - mu) * rs * gamma[col] + beta[col];
        }
    }
}

// ---------------------------------------------------------------------------
extern "C" void kernel_launch(void* const* d_in, const int* in_sizes, int n_in,
                              void* d_out, int out_size, void* d_ws, size_t ws_size,
                              hipStream_t stream)
{
    const float* hidden   = (const float*)d_in[0];
    const float* time_emb = (const float*)d_in[1];
    const int*   eidx     = (const int*)d_in[2];
    const int*   etype    = (const int*)d_in[3];
    const float* edge_emb = (const float*)d_in[4];
    const float* Wq = (const float*)d_in[5];
    const float* bq = (const float*)d_in[6];
    const float* Wk = (const float*)d_in[7];
    const float* bk = (const float*)d_in[8];
    const float* Wv = (const float*)d_in[9];
    const float* bv = (const float*)d_in[10];
    const float* We = (const float*)d_in[11];
    const float* be = (const float*)d_in[12];
    const float* W1 = (const float*)d_in[13];
    const float* b1 = (const float*)d_in[14];
    const float* W2 = (const float*)d_in[15];
    const float* b2 = (const float*)d_in[16];
    const float* gamma = (const float*)d_in[17];
    const float* beta  = (const float*)d_in[18];
    float* out = (float*)d_out;

    constexpr int BNH = B_ * N_ * H_;
    u16* Qb   = (u16*)d_ws;                 // B*N*128 bf16
    u16* KVb  = Qb + BNH;                   // B*N*256 bf16 (K|V interleaved)
    u16* aggb = KVb + (size_t)B_ * N_ * 256;
    float* Kt  = (float*)(aggb + BNH);
    float* Vt  = Kt + ET_ * H_;
    float* ebt = Vt + ET_ * H_;
    int* count = (int*)(ebt + ET_);
    int* slots = count + N_;                // N*CAP ints
    uintptr_t wp = (uintptr_t)(slots + N_ * CAP_);
    wp = (wp + 15) & ~(uintptr_t)15;
    u16* W1s = (u16*)wp;
    u16* W2s = W1s + 384 * 128;
    u16* Wqs = W2s + 128 * 128;
    u16* Wks = Wqs + 128 * 128;
    u16* Wvs = Wks + 128 * 128;

    const int* esrc = eidx;
    const int* etgt = eidx + E_;

    setup_kernel<<<74, 256, 0, stream>>>(
        W1, W2, Wq, Wk, Wv, W1s, W2s, Wqs, Wks, Wvs,
        edge_emb, bk, bv, We, be, Kt, Vt, ebt, count);
    scatter_qkv_kernel<<<625 + 313, 256, 0, stream>>>(
        esrc, etgt, etype, count, slots,
        hidden, time_emb, Wqs, Wks, Wvs, bq, Qb, KVb);
    attn_kernel<<<(B_ * N_) / 4, 256, 0, stream>>>(
        Qb, KVb, Kt, Vt, ebt, count, slots, aggb);
    mlp_mfma_kernel<<<313, 256, 0, stream>>>(
        hidden, aggb, time_emb, W1s, W2s, b1, b2, gamma, beta, out);
}

// Round 8
// 172.591 us; speedup vs baseline: 1.2249x; 1.0119x over previous
//
#include <hip/hip_runtime.h>
#include <math.h>

constexpr int B_  = 2;
constexpr int N_  = 10000;
constexpr int E_  = 160000;
constexpr int H_  = 128;
constexpr int ET_ = 8;
constexpr int CAP_ = 64;               // slots per tgt node; P(deg>=64) ~ 2e-18
constexpr float EPS_ = 1e-5f;
constexpr float RSQH = 0.08838834764831845f; // 1/sqrt(128)

typedef __bf16 bf16x8 __attribute__((ext_vector_type(8)));
typedef short  short8 __attribute__((ext_vector_type(8)));
typedef float  f32x4  __attribute__((ext_vector_type(4)));
typedef unsigned short u16;

__device__ inline u16 bf16b(float f) {
    return __builtin_bit_cast(u16, (__bf16)f);
}

__device__ inline bf16x8 ldfrag(const u16* __restrict__ W, int kc, int nt, int lane) {
    short8 s = *(const short8*)(W + ((kc * 8 + nt) * 64 + lane) * 8);
    return __builtin_bit_cast(bf16x8, s);
}

// ---------------------------------------------------------------------------
// Setup: blocks [0,56) weight-prep, [56,64) edge-type tables,
// [64,74) zero count[].  (unchanged from R7)
// ---------------------------------------------------------------------------
__global__ __launch_bounds__(256)
void setup_kernel(const float* __restrict__ W1, const float* __restrict__ W2,
                  const float* __restrict__ Wq, const float* __restrict__ Wk,
                  const float* __restrict__ Wv,
                  u16* __restrict__ W1s, u16* __restrict__ W2s,
                  u16* __restrict__ Wqs, u16* __restrict__ Wks, u16* __restrict__ Wvs,
                  const float* __restrict__ edge_emb,
                  const float* __restrict__ bk, const float* __restrict__ bv,
                  const float* __restrict__ We, const float* __restrict__ be,
                  float* __restrict__ Kt, float* __restrict__ Vt, float* __restrict__ eb,
                  int* __restrict__ count)
{
    const int bid = blockIdx.x, tid = threadIdx.x;
    if (bid < 56) {
        int unit = bid >> 1, half = bid & 1;
        const float* src; u16* dst; int kc;
        if (unit < 12)      { src = W1; dst = W1s; kc = unit; }
        else if (unit < 16) { src = W2; dst = W2s; kc = unit - 12; }
        else if (unit < 20) { src = Wq; dst = Wqs; kc = unit - 16; }
        else if (unit < 24) { src = Wk; dst = Wks; kc = unit - 20; }
        else                { src = Wv; dst = Wvs; kc = unit - 24; }
        int nt = half * 4 + (tid >> 6), lane = tid & 63;
        int q = lane >> 4, c = lane & 15;
        int kbase = kc * 32 + q * 8;
        int col = nt * 16 + c;
        u16* out = dst + ((kc * 8 + nt) * 64 + lane) * 8;
#pragma unroll
        for (int j = 0; j < 8; ++j)
            out[j] = bf16b(src[(kbase + j) * H_ + col]);
    } else if (bid < 64) {
        int t = bid - 56;
        const float* ep = edge_emb + t * H_;
        __shared__ float red[2];
        int j = tid;
        if (j < 128) {
            float ak = bk[j], av = bv[j];
            for (int d = 0; d < H_; d += 4) {
                float e0 = ep[d], e1 = ep[d+1], e2 = ep[d+2], e3 = ep[d+3];
                ak += e0*Wk[(d+0)*H_+j] + e1*Wk[(d+1)*H_+j] + e2*Wk[(d+2)*H_+j] + e3*Wk[(d+3)*H_+j];
                av += e0*Wv[(d+0)*H_+j] + e1*Wv[(d+1)*H_+j] + e2*Wv[(d+2)*H_+j] + e3*Wv[(d+3)*H_+j];
            }
            Kt[t*H_ + j] = ak;
            Vt[t*H_ + j] = av;
            float pe = ep[j] * We[j];
#pragma unroll
            for (int off = 32; off; off >>= 1) pe += __shfl_xor(pe, off);
            if ((j & 63) == 0) red[j >> 6] = pe;
        }
        __syncthreads();
        if (j == 0) eb[t] = red[0] + red[1] + be[0];
    } else {
        int i0 = (bid - 64) * 1024;
        for (int i = i0 + tid; i < i0 + 1024; i += 256)
            if (i < N_) count[i] = 0;
    }
}

// ---------------------------------------------------------------------------
// Fused scatter (blocks [0,625)) + Q/KV MFMA (blocks [625,938)).  Unchanged.
// ---------------------------------------------------------------------------
__global__ __launch_bounds__(256)
void scatter_qkv_kernel(const int* __restrict__ src, const int* __restrict__ tgt,
                        const int* __restrict__ type, int* __restrict__ count,
                        int* __restrict__ slots,
                        const float* __restrict__ hidden, const float* __restrict__ time_emb,
                        const u16* __restrict__ Wqs, const u16* __restrict__ Wks,
                        const u16* __restrict__ Wvs, const float* __restrict__ bq,
                        u16* __restrict__ Q, u16* __restrict__ KV)
{
    if (blockIdx.x < 625) {
        int e = blockIdx.x * 256 + threadIdx.x;
        if (e < E_) {
            int t = tgt[e];
            int pos = atomicAdd(&count[t], 1);
            slots[t * CAP_ + pos] = src[e] | (type[e] << 16);
        }
        return;
    }
    const int wv = threadIdx.x >> 6, lane = threadIdx.x & 63;
    const int tile = (blockIdx.x - 625) * 4 + wv;
    if (tile >= (B_ * N_) / 16) return;
    const int nbase = tile * 16;
    const int m = lane & 15, q = lane >> 4;
    const int koff = q * 8;

    bf16x8 aq[4], av[4];
    const float* hp = hidden   + (nbase + m) * H_ + koff;
    const float* tp = time_emb + (nbase + m) * H_ + koff;
#pragma unroll
    for (int kc = 0; kc < 4; ++kc) {
        float4 h0 = *(const float4*)(hp + kc * 32);
        float4 h1 = *(const float4*)(hp + kc * 32 + 4);
        float4 t0 = *(const float4*)(tp + kc * 32);
        float4 t1 = *(const float4*)(tp + kc * 32 + 4);
        bf16x8 fv, fq;
        fv[0]=(__bf16)h0.x; fv[1]=(__bf16)h0.y; fv[2]=(__bf16)h0.z; fv[3]=(__bf16)h0.w;
        fv[4]=(__bf16)h1.x; fv[5]=(__bf16)h1.y; fv[6]=(__bf16)h1.z; fv[7]=(__bf16)h1.w;
        fq[0]=(__bf16)(h0.x+t0.x); fq[1]=(__bf16)(h0.y+t0.y);
        fq[2]=(__bf16)(h0.z+t0.z); fq[3]=(__bf16)(h0.w+t0.w);
        fq[4]=(__bf16)(h1.x+t1.x); fq[5]=(__bf16)(h1.y+t1.y);
        fq[6]=(__bf16)(h1.z+t1.z); fq[7]=(__bf16)(h1.w+t1.w);
        av[kc] = fv; aq[kc] = fq;
    }

    f32x4 accq[8], acck[8], accv[8];
#pragma unroll
    for (int nt = 0; nt < 8; ++nt) { accq[nt] = (f32x4)0.f; acck[nt] = (f32x4)0.f; accv[nt] = (f32x4)0.f; }

#pragma unroll
    for (int kc = 0; kc < 4; ++kc) {
#pragma unroll
        for (int nt = 0; nt < 8; ++nt) {
            bf16x8 bfq = ldfrag(Wqs, kc, nt, lane);
            bf16x8 bfk = ldfrag(Wks, kc, nt, lane);
            bf16x8 bfv = ldfrag(Wvs, kc, nt, lane);
            accq[nt] = __builtin_amdgcn_mfma_f32_16x16x32_bf16(aq[kc], bfq, accq[nt], 0, 0, 0);
            acck[nt] = __builtin_amdgcn_mfma_f32_16x16x32_bf16(aq[kc], bfk, acck[nt], 0, 0, 0);
            accv[nt] = __builtin_amdgcn_mfma_f32_16x16x32_bf16(av[kc], bfv, accv[nt], 0, 0, 0);
        }
    }

#pragma unroll
    for (int nt = 0; nt < 8; ++nt) {
        int col = nt * 16 + m;
        float bqc = bq[col];
#pragma unroll
        for (int r = 0; r < 4; ++r) {
            int node = nbase + q * 4 + r;
            Q[(size_t)node * H_ + col] = bf16b(accq[nt][r] + bqc);
            KV[(size_t)node * 256 + col]       = bf16b(acck[nt][r]);
            KV[(size_t)node * 256 + 128 + col] = bf16b(accv[nt][r]);
        }
    }
}

// ---------------------------------------------------------------------------
// Attention (R7 + slot preload): one wave per (b,node); groups of 16 lanes;
// single-pass online softmax, deferred rescale (THR=8); 2 edges in flight.
// NEW: the node's slot list is preloaded once — lane lam of group g holds
// slots[g + 4*lam] (one coalesced 256-B wave load) — and per-round edge words
// come from in-group __shfl (2 ds_bpermute) instead of 2 L2 loads, removing
// the slot->KV pointer-chase from the critical path.  Shfl safety: cnt and c
// are group-uniform, so all 16 lanes of a group stay converged and shfl
// sources are always within the active group.
// ---------------------------------------------------------------------------
__global__ __launch_bounds__(256)
void attn_kernel(const u16* __restrict__ Qb, const u16* __restrict__ KV,
                 const float* __restrict__ Kt, const float* __restrict__ Vt,
                 const float* __restrict__ eb,
                 const int* __restrict__ count, const int* __restrict__ slots,
                 u16* __restrict__ aggb)
{
    __shared__ float bias_s[4][8];
    __shared__ __align__(16) u16 vt_s[8][128];

    const int tid = threadIdx.x;
    const int wv = tid >> 6, lane = tid & 63;
    const int g = lane >> 4, lam = lane & 15;

    for (int idx = tid; idx < ET_ * H_; idx += 256)
        vt_s[idx >> 7][idx & 127] = bf16b(Vt[idx]);
    __syncthreads();

    const int b = (blockIdx.x >= (N_ / 4)) ? 1 : 0;   // batch-contiguous halves
    const int n = (blockIdx.x - b * (N_ / 4)) * 4 + wv;
    const int bn = b * N_ + n;
    const int cnt = count[n];
    const int sbase = n * CAP_;
    const u16* __restrict__ KVb = KV + (size_t)(b * N_) * 256;

    // preload slot list: lane lam of group g holds edge g + 4*lam
    int myslot = 0;
    {
        int idx = g + 4 * lam;
        if (idx < cnt) myslot = slots[sbase + idx];
    }
    const int lb = lane & 48;    // group base lane

    float q[8];
    {
        short8 s8 = *(const short8*)(Qb + (size_t)bn * H_ + lam * 8);
        bf16x8 qa = __builtin_bit_cast(bf16x8, s8);
#pragma unroll
        for (int j = 0; j < 8; ++j) q[j] = (float)qa[j];
    }

    {   // per-type logit bias: group g computes types 2g, 2g+1
        const float* k0p = Kt + (2 * g) * H_ + lam * 8;
        const float* k1p = Kt + (2 * g + 1) * H_ + lam * 8;
        float p0 = 0.f, p1 = 0.f;
#pragma unroll
        for (int j = 0; j < 8; ++j) { p0 += q[j] * k0p[j]; p1 += q[j] * k1p[j]; }
#pragma unroll
        for (int msk = 1; msk < 16; msk <<= 1) {
            p0 += __shfl_xor(p0, msk);
            p1 += __shfl_xor(p1, msk);
        }
        if (lam == 0) {
            bias_s[wv][2 * g]     = p0 * RSQH + eb[2 * g];
            bias_s[wv][2 * g + 1] = p1 * RSQH + eb[2 * g + 1];
        }
    }
    // bias_s row written/read by the same wave -> wave-synchronous

    float m_g = -INFINITY, l_g = 0.f;
    float acc[8];
#pragma unroll
    for (int j = 0; j < 8; ++j) acc[j] = 0.f;

    int c = g;
    for (; c + 4 < cnt; c += 8) {
        int r = (c - g) >> 2;                 // 0,2,4,...
        int pk0 = __shfl(myslot, lb + r);
        int pk1 = __shfl(myslot, lb + r + 1);
        int s0 = pk0 & 0xFFFF, t0 = pk0 >> 16;
        int s1 = pk1 & 0xFFFF, t1 = pk1 >> 16;
        // co-issue K and V for both edges (one 512-B region per edge)
        short8 k80 = *(const short8*)(KVb + (size_t)s0 * 256 + lam * 8);
        short8 k81 = *(const short8*)(KVb + (size_t)s1 * 256 + lam * 8);
        short8 v80 = *(const short8*)(KVb + (size_t)s0 * 256 + 128 + lam * 8);
        short8 v81 = *(const short8*)(KVb + (size_t)s1 * 256 + 128 + lam * 8);
        short8 vt80 = *(const short8*)(&vt_s[t0][lam * 8]);
        short8 vt81 = *(const short8*)(&vt_s[t1][lam * 8]);
        bf16x8 ka0 = __builtin_bit_cast(bf16x8, k80);
        bf16x8 ka1 = __builtin_bit_cast(bf16x8, k81);
        float p0 = 0.f, p1 = 0.f;
#pragma unroll
        for (int j = 0; j < 8; ++j) {
            p0 += q[j] * (float)ka0[j];
            p1 += q[j] * (float)ka1[j];
        }
#pragma unroll
        for (int msk = 1; msk < 16; msk <<= 1) {
            p0 += __shfl_xor(p0, msk);
            p1 += __shfl_xor(p1, msk);
        }
        float lg0 = p0 * RSQH + bias_s[wv][t0];
        float lg1 = p1 * RSQH + bias_s[wv][t1];
        float mx = fmaxf(lg0, lg1);
        if (mx > m_g + 8.f) {          // deferred rescale (T13)
            float rs = __expf(m_g - mx);   // first trigger: exp(-inf)=0
            l_g *= rs;
#pragma unroll
            for (int j = 0; j < 8; ++j) acc[j] *= rs;
            m_g = mx;
        }
        float w0 = __expf(lg0 - m_g);
        float w1 = __expf(lg1 - m_g);
        l_g += w0 + w1;
        bf16x8 va0  = __builtin_bit_cast(bf16x8, v80);
        bf16x8 va1  = __builtin_bit_cast(bf16x8, v81);
        bf16x8 vta0 = __builtin_bit_cast(bf16x8, vt80);
        bf16x8 vta1 = __builtin_bit_cast(bf16x8, vt81);
#pragma unroll
        for (int j = 0; j < 8; ++j)
            acc[j] += w0 * ((float)va0[j] + (float)vta0[j])
                    + w1 * ((float)va1[j] + (float)vta1[j]);
    }
    if (c < cnt) {
        int r = (c - g) >> 2;
        int pk0 = __shfl(myslot, lb + r);
        int s0 = pk0 & 0xFFFF, t0 = pk0 >> 16;
        short8 k80 = *(const short8*)(KVb + (size_t)s0 * 256 + lam * 8);
        short8 v80 = *(const short8*)(KVb + (size_t)s0 * 256 + 128 + lam * 8);
        short8 vt80 = *(const short8*)(&vt_s[t0][lam * 8]);
        bf16x8 ka0 = __builtin_bit_cast(bf16x8, k80);
        float p0 = 0.f;
#pragma unroll
        for (int j = 0; j < 8; ++j) p0 += q[j] * (float)ka0[j];
#pragma unroll
        for (int msk = 1; msk < 16; msk <<= 1) p0 += __shfl_xor(p0, msk);
        float lg0 = p0 * RSQH + bias_s[wv][t0];
        if (lg0 > m_g + 8.f) {
            float rs = __expf(m_g - lg0);
            l_g *= rs;
#pragma unroll
            for (int j = 0; j < 8; ++j) acc[j] *= rs;
            m_g = lg0;
        }
        float w0 = __expf(lg0 - m_g);
        l_g += w0;
        bf16x8 va0  = __builtin_bit_cast(bf16x8, v80);
        bf16x8 vta0 = __builtin_bit_cast(bf16x8, vt80);
#pragma unroll
        for (int j = 0; j < 8; ++j)
            acc[j] += w0 * ((float)va0[j] + (float)vta0[j]);
    }

    // merge the 4 groups (reconverged here): max + rescale + sum
    float M = fmaxf(m_g, __shfl_xor(m_g, 16));
    M = fmaxf(M, __shfl_xor(M, 32));
    float rs = (m_g == M) ? 1.f : __expf(m_g - M);  // guards -inf - -inf = NaN
    l_g *= rs;
#pragma unroll
    for (int j = 0; j < 8; ++j) {
        acc[j] *= rs;
        acc[j] += __shfl_xor(acc[j], 16);
        acc[j] += __shfl_xor(acc[j], 32);
    }
    l_g += __shfl_xor(l_g, 16);
    l_g += __shfl_xor(l_g, 32);

    if (g == 0) {
        float invL = (cnt > 0) ? 1.f / l_g : 0.f;
        bf16x8 o;
#pragma unroll
        for (int j = 0; j < 8; ++j) o[j] = (__bf16)(acc[j] * invL);
        *(short8*)(aggb + (size_t)bn * H_ + lam * 8) = __builtin_bit_cast(short8, o);
    }
}

// ---------------------------------------------------------------------------
// MLP + residual + LayerNorm via MFMA.  313 blocks x 4 waves.  Unchanged.
// ---------------------------------------------------------------------------
__global__ __launch_bounds__(256)
void mlp_mfma_kernel(const float* __restrict__ hidden, const u16* __restrict__ aggb,
                     const float* __restrict__ time_emb,
                     const u16* __restrict__ W1s, const u16* __restrict__ W2s,
                     const float* __restrict__ b1, const float* __restrict__ b2,
                     const float* __restrict__ gamma, const float* __restrict__ beta,
                     float* __restrict__ out)
{
    __shared__ __align__(16) u16 h1s[4][16][136];
    const int wv = threadIdx.x >> 6, lane = threadIdx.x & 63;
    const int tile = blockIdx.x * 4 + wv;
    if (tile >= (B_ * N_) / 16) return;
    const int nbase = tile * 16;
    const int m = lane & 15, q = lane >> 4;
    const int koff = q * 8;

    bf16x8 a[12];
    const float* hp = hidden   + (nbase + m) * H_ + koff;
    const float* tp = time_emb + (nbase + m) * H_ + koff;
    const u16*   ap = aggb + (size_t)(nbase + m) * H_ + koff;
#pragma unroll
    for (int kc = 0; kc < 4; ++kc) {
        float4 h0 = *(const float4*)(hp + kc * 32);
        float4 h1 = *(const float4*)(hp + kc * 32 + 4);
        float4 t0 = *(const float4*)(tp + kc * 32);
        float4 t1 = *(const float4*)(tp + kc * 32 + 4);
        bf16x8 fh, ft;
        fh[0]=(__bf16)h0.x; fh[1]=(__bf16)h0.y; fh[2]=(__bf16)h0.z; fh[3]=(__bf16)h0.w;
        fh[4]=(__bf16)h1.x; fh[5]=(__bf16)h1.y; fh[6]=(__bf16)h1.z; fh[7]=(__bf16)h1.w;
        ft[0]=(__bf16)t0.x; ft[1]=(__bf16)t0.y; ft[2]=(__bf16)t0.z; ft[3]=(__bf16)t0.w;
        ft[4]=(__bf16)t1.x; ft[5]=(__bf16)t1.y; ft[6]=(__bf16)t1.z; ft[7]=(__bf16)t1.w;
        a[0 * 4 + kc] = fh;
        a[2 * 4 + kc] = ft;
        short8 s8 = *(const short8*)(ap + kc * 32);
        a[1 * 4 + kc] = __builtin_bit_cast(bf16x8, s8);
    }

    f32x4 acc[8];
#pragma unroll
    for (int nt = 0; nt < 8; ++nt) acc[nt] = (f32x4)0.f;
#pragma unroll
    for (int kc = 0; kc < 12; ++kc) {
#pragma unroll
        for (int nt = 0; nt < 8; ++nt) {
            bf16x8 bf = ldfrag(W1s, kc, nt, lane);
            acc[nt] = __builtin_amdgcn_mfma_f32_16x16x32_bf16(a[kc], bf, acc[nt], 0, 0, 0);
        }
    }

#pragma unroll
    for (int nt = 0; nt < 8; ++nt) {
        int col = nt * 16 + m;
        float bb = b1[col];
#pragma unroll
        for (int r = 0; r < 4; ++r) {
            float v = acc[nt][r] + bb;
            float h = v / (1.f + __expf(-v));
            h1s[wv][q * 4 + r][col] = bf16b(h);
        }
    }

    f32x4 acc2[8];
#pragma unroll
    for (int nt = 0; nt < 8; ++nt) acc2[nt] = (f32x4)0.f;
#pragma unroll
    for (int kc = 0; kc < 4; ++kc) {
        short8 s8 = *(const short8*)&h1s[wv][m][kc * 32 + koff];
        bf16x8 a2 = __builtin_bit_cast(bf16x8, s8);
#pragma unroll
        for (int nt = 0; nt < 8; ++nt) {
            bf16x8 bf = ldfrag(W2s, kc, nt, lane);
            acc2[nt] = __builtin_amdgcn_mfma_f32_16x16x32_bf16(a2, bf, acc2[nt], 0, 0, 0);
        }
    }

    float x[8][4];
#pragma unroll
    for (int nt = 0; nt < 8; ++nt) {
        int col = nt * 16 + m;
        float bb = b2[col];
#pragma unroll
        for (int r = 0; r < 4; ++r) {
            int node = nbase + q * 4 + r;
            x[nt][r] = hidden[node * H_ + col] + acc2[nt][r] + bb;
        }
    }
#pragma unroll
    for (int r = 0; r < 4; ++r) {
        float s = 0.f, ss = 0.f;
#pragma unroll
        for (int nt = 0; nt < 8; ++nt) { s += x[nt][r]; ss += x[nt][r] * x[nt][r]; }
#pragma unroll
        for (int off = 1; off < 16; off <<= 1) {
            s  += __shfl_xor(s, off);
            ss += __shfl_xor(ss, off);
        }
        float mu  = s * (1.f / H_);
        float var = ss * (1.f / H_) - mu * mu;
        float rs  = rsqrtf(var + EPS_);
        int node = nbase + q * 4 + r;
#pragma unroll
        for (int nt = 0; nt < 8; ++nt) {
            int col = nt * 16 + m;
            out[node * H_ + col] = (x[nt][r] - mu) * rs * gamma[col] + beta[col];
        }
    }
}

// ---------------------------------------------------------------------------
extern "C" void kernel_launch(void* const* d_in, const int* in_sizes, int n_in,
                              void* d_out, int out_size, void* d_ws, size_t ws_size,
                              hipStream_t stream)
{
    const float* hidden   = (const float*)d_in[0];
    const float* time_emb = (const float*)d_in[1];
    const int*   eidx     = (const int*)d_in[2];
    const int*   etype    = (const int*)d_in[3];
    const float* edge_emb = (const float*)d_in[4];
    const float* Wq = (const float*)d_in[5];
    const float* bq = (const float*)d_in[6];
    const float* Wk = (const float*)d_in[7];
    const float* bk = (const float*)d_in[8];
    const float* Wv = (const float*)d_in[9];
    const float* bv = (const float*)d_in[10];
    const float* We = (const float*)d_in[11];
    const float* be = (const float*)d_in[12];
    const float* W1 = (const float*)d_in[13];
    const float* b1 = (const float*)d_in[14];
    const float* W2 = (const float*)d_in[15];
    const float* b2 = (const float*)d_in[16];
    const float* gamma = (const float*)d_in[17];
    const float* beta  = (const float*)d_in[18];
    float* out = (float*)d_out;

    constexpr int BNH = B_ * N_ * H_;
    u16* Qb   = (u16*)d_ws;                 // B*N*128 bf16
    u16* KVb  = Qb + BNH;                   // B*N*256 bf16 (K|V interleaved)
    u16* aggb = KVb + (size_t)B_ * N_ * 256;
    float* Kt  = (float*)(aggb + BNH);
    float* Vt  = Kt + ET_ * H_;
    float* ebt = Vt + ET_ * H_;
    int* count = (int*)(ebt + ET_);
    int* slots = count + N_;                // N*CAP ints
    uintptr_t wp = (uintptr_t)(slots + N_ * CAP_);
    wp = (wp + 15) & ~(uintptr_t)15;
    u16* W1s = (u16*)wp;
    u16* W2s = W1s + 384 * 128;
    u16* Wqs = W2s + 128 * 128;
    u16* Wks = Wqs + 128 * 128;
    u16* Wvs = Wks + 128 * 128;

    const int* esrc = eidx;
    const int* etgt = eidx + E_;

    setup_kernel<<<74, 256, 0, stream>>>(
        W1, W2, Wq, Wk, Wv, W1s, W2s, Wqs, Wks, Wvs,
        edge_emb, bk, bv, We, be, Kt, Vt, ebt, count);
    scatter_qkv_kernel<<<625 + 313, 256, 0, stream>>>(
        esrc, etgt, etype, count, slots,
        hidden, time_emb, Wqs, Wks, Wvs, bq, Qb, KVb);
    attn_kernel<<<(B_ * N_) / 4, 256, 0, stream>>>(
        Qb, KVb, Kt, Vt, ebt, count, slots, aggb);
    mlp_mfma_kernel<<<313, 256, 0, stream>>>(
        hidden, aggb, time_emb, W1s, W2s, b1, b2, gamma, beta, out);
}